// Round 6
// baseline (273.626 us; speedup 1.0000x reference)
//
#include <hip/hip_runtime.h>

// NT-Xent loss, B=4096, D=256, N=16384, T=0.5.
// loss = mean_i( -pos_i + log(sum_{j!=i} exp(2*dot(zn_i, zn_j)) + 1e-12) )
//
// R6 = R2's verified bf16 staged kernel with:
//  - BALANCED supertile-sequential triangle decode (grid=8256, no early exit).
//    R5's xcd-bit swizzle mapped bid&7 -> supertile COLUMN; triangle columns
//    have 136..1928 working blocks -> 1.87x XCD imbalance (= measured 188/104).
//    Now consecutive bids fill one supertile at a time: balanced + L2-local.
//  - LDS cut to exactly 32768B (reduction scratch aliased over dead tile LDS)
//    -> 5 blocks/CU cap (was 4), __launch_bounds__(256,5).
//  - zb prescaled by sqrt(2/ln2): epilogue exp = one v_exp_f32 (R5-verified).
//
// ws layout:
//   [0, 8MB)            : zb   — l2-normalized z * sqrt(2/ln2), bf16, [16384][256]
//   [8MB, 16MB)         : part — per-colblock row sums, f32, [128][16384]
//   [16MB, 16MB+16KB)   : pospart[4096]
//   [16MB+16KB, +1KB)   : logpart[256]
// Every ws slot is written exactly once per launch -> no memset needed.

typedef __bf16 bf16;
typedef __bf16 bf16x4 __attribute__((ext_vector_type(4)));
typedef __bf16 bf16x8 __attribute__((ext_vector_type(8)));
typedef float  f32x4  __attribute__((ext_vector_type(4)));

#define NTOT 16384
#define DDIM 256
#define PRESCALE 1.69864359f  // sqrt(2/ln2); acc = (2/ln2)*cos_sim, e = exp2(acc)

__device__ __forceinline__ float dot4(float4 a, float4 b) {
    return a.x * b.x + a.y * b.y + a.z * b.z + a.w * b.w;
}

// ---------------- kernel 1: normalize rows -> bf16*sqrt(2/ln2), plus positive pairs ----------------
__global__ __launch_bounds__(256) void norm4k(const float* __restrict__ z1,
                                              const float* __restrict__ z2,
                                              const float* __restrict__ z3,
                                              const float* __restrict__ z4,
                                              bf16* __restrict__ zb,
                                              float* __restrict__ pospart) {
    const int wave = threadIdx.x >> 6;
    const int lane = threadIdx.x & 63;
    const int i    = blockIdx.x * 4 + wave; // 0..4095
    const float4* p1 = (const float4*)(z1 + (size_t)i * DDIM);
    const float4* p2 = (const float4*)(z2 + (size_t)i * DDIM);
    const float4* p3 = (const float4*)(z3 + (size_t)i * DDIM);
    const float4* p4 = (const float4*)(z4 + (size_t)i * DDIM);
    float4 a = p1[lane], b = p2[lane], c = p3[lane], d = p4[lane];
    float s11 = dot4(a, a), s22 = dot4(b, b), s33 = dot4(c, c), s44 = dot4(d, d);
    float s12 = dot4(a, b), s23 = dot4(b, c), s34 = dot4(c, d), s41 = dot4(d, a);
#pragma unroll
    for (int m = 32; m >= 1; m >>= 1) {
        s11 += __shfl_xor(s11, m, 64); s22 += __shfl_xor(s22, m, 64);
        s33 += __shfl_xor(s33, m, 64); s44 += __shfl_xor(s44, m, 64);
        s12 += __shfl_xor(s12, m, 64); s23 += __shfl_xor(s23, m, 64);
        s34 += __shfl_xor(s34, m, 64); s41 += __shfl_xor(s41, m, 64);
    }
    const float m1 = fmaxf(sqrtf(s11), 1e-12f), m2 = fmaxf(sqrtf(s22), 1e-12f);
    const float m3 = fmaxf(sqrtf(s33), 1e-12f), m4 = fmaxf(sqrtf(s44), 1e-12f);
    const float i1 = 1.0f / m1, i2 = 1.0f / m2, i3 = 1.0f / m3, i4 = 1.0f / m4;
    const float a1 = i1 * PRESCALE, a2 = i2 * PRESCALE, a3 = i3 * PRESCALE, a4 = i4 * PRESCALE;
    bf16x4 o;
    o.x = (bf16)(a.x * a1); o.y = (bf16)(a.y * a1); o.z = (bf16)(a.z * a1); o.w = (bf16)(a.w * a1);
    *(bf16x4*)(zb + (size_t)i * DDIM + lane * 4) = o;
    o.x = (bf16)(b.x * a2); o.y = (bf16)(b.y * a2); o.z = (bf16)(b.z * a2); o.w = (bf16)(b.w * a2);
    *(bf16x4*)(zb + (size_t)(i + 4096) * DDIM + lane * 4) = o;
    o.x = (bf16)(c.x * a3); o.y = (bf16)(c.y * a3); o.z = (bf16)(c.z * a3); o.w = (bf16)(c.w * a3);
    *(bf16x4*)(zb + (size_t)(i + 8192) * DDIM + lane * 4) = o;
    o.x = (bf16)(d.x * a4); o.y = (bf16)(d.y * a4); o.z = (bf16)(d.z * a4); o.w = (bf16)(d.w * a4);
    *(bf16x4*)(zb + (size_t)(i + 12288) * DDIM + lane * 4) = o;
    if (lane == 0)
        pospart[i] = 2.0f * (s12 * i1 * i2 + s23 * i2 * i3 + s34 * i3 * i4 + s41 * i4 * i1);
}

// ---------------- kernel 2: fused Gram exp-rowsum, balanced supertile triangle ----------------
// 128x128 tile per block; 4 waves in 2x2 of 64x64; mfma_f32_16x16x32_bf16.
// LDS granule-xor swizzle: granule g of row r stored at slot (g ^ (r&7)).
__global__ __launch_bounds__(256, 5) void tilek(const bf16* __restrict__ zb,
                                                float* __restrict__ part) {
    __shared__ __attribute__((aligned(16))) char lds[32768]; // A:[0,16K) B:[16K,32K)
    // reduction scratch aliased over dead tile LDS after the final K-barrier:
    float* rsum = (float*)lds;            // [2][128] (indexed by wc)
    float* csum = (float*)(lds + 1024);   // [2][128] (indexed by wr)

    const int tid  = threadIdx.x;
    const int wave = tid >> 6;
    const int lane = tid & 63;

    // Balanced supertile-sequential triangle decode (8x8 supertiles of 16x16
    // blocks). Supertile row r: diag supertile (136 triangle blocks) then
    // (7-r) full off-diag supertiles (256 each). Consecutive bids share a
    // supertile -> all XCDs work the same ~2MB set; zero early exits.
    int rem = blockIdx.x;
    int sr = 0;
#pragma unroll
    for (int r = 0; r < 7; ++r) {
        int rowblocks = 136 + (7 - sr) * 256;
        if (rem >= rowblocks) { rem -= rowblocks; ++sr; }
    }
    int brow, bcol;
    if (rem < 136) {  // diagonal supertile (sr,sr): 16-row triangle
        int i = 0;
#pragma unroll
        for (int r = 0; r < 15; ++r) {
            if (rem >= 16 - i) { rem -= 16 - i; ++i; }
        }
        brow = sr * 16 + i;
        bcol = sr * 16 + i + rem;
    } else {
        int e  = rem - 136;
        int sc = sr + 1 + (e >> 8);
        int w  = e & 255;
        brow = sr * 16 + (w >> 4);
        bcol = sc * 16 + (w & 15);
    }
    const bool isdiag = (brow == bcol);

    const char* gA = (const char*)zb + (size_t)brow * 128 * 512; // row stride 512B
    const char* gB = (const char*)zb + (size_t)bcol * 128 * 512;

    const int quad = lane >> 4;
    const int l15  = lane & 15;
    const int wr   = wave >> 1, wc = wave & 1;

    f32x4 zero = {0.f, 0.f, 0.f, 0.f};
    f32x4 acc[4][4];
#pragma unroll
    for (int a = 0; a < 4; ++a)
#pragma unroll
        for (int b = 0; b < 4; ++b) acc[a][b] = zero;

    const int strow = lane >> 3;  // row within 8-row chunk
    const int sslot = lane & 7;   // swizzled granule slot this lane fills

    for (int ko = 0; ko < 4; ++ko) {
        // stage A and B 128x64 slices (16KB each); 4+4 1KB wave-loads per wave
#pragma unroll
        for (int s4 = 0; s4 < 4; ++s4) {
            int t   = (wave << 2) + s4;        // 0..15
            int row = (t << 3) + strow;        // 0..127
            int g   = sslot ^ (row & 7);       // global granule to fetch
            size_t goff = (size_t)row * 512 + ko * 128 + g * 16;
            __builtin_amdgcn_global_load_lds(
                (const __attribute__((address_space(1))) unsigned int*)(gA + goff),
                (__attribute__((address_space(3))) unsigned int*)(lds + t * 1024),
                16, 0, 0);
            __builtin_amdgcn_global_load_lds(
                (const __attribute__((address_space(1))) unsigned int*)(gB + goff),
                (__attribute__((address_space(3))) unsigned int*)(lds + 16384 + t * 1024),
                16, 0, 0);
        }
        __syncthreads();
#pragma unroll
        for (int ks = 0; ks < 2; ++ks) {
            bf16x8 af[4], bfr[4];
            const int gg = (ks << 2) + quad;   // granule within 64-col slice
#pragma unroll
            for (int rt = 0; rt < 4; ++rt) {
                int arow = (wr << 6) + (rt << 4) + l15;
                int addr = arow * 128 + ((gg ^ (arow & 7)) << 4);
                af[rt] = *(const bf16x8*)(lds + addr);
            }
#pragma unroll
            for (int ct = 0; ct < 4; ++ct) {
                int brw  = (wc << 6) + (ct << 4) + l15;
                int addr = 16384 + brw * 128 + ((gg ^ (brw & 7)) << 4);
                bfr[ct] = *(const bf16x8*)(lds + addr);
            }
#pragma unroll
            for (int rt = 0; rt < 4; ++rt)
#pragma unroll
                for (int ct = 0; ct < 4; ++ct)
                    acc[rt][ct] = __builtin_amdgcn_mfma_f32_16x16x32_bf16(
                        af[rt], bfr[ct], acc[rt][ct], 0, 0, 0);
        }
        __syncthreads();   // final iter: all tile reads done -> scratch aliasing safe
    }

    // epilogue: e = exp2(acc) (inputs pre-scaled by sqrt(2/ln2)); mask diagonal;
    // row-sums over lane&15, col-sums over quad.
    const int rb = wr << 6;
    const int cb = wc << 6;
    float cs[4] = {0.f, 0.f, 0.f, 0.f};
#pragma unroll
    for (int rt = 0; rt < 4; ++rt) {
        float rs[4] = {0.f, 0.f, 0.f, 0.f};
        const int rtile = rb + (rt << 4);
#pragma unroll
        for (int ct = 0; ct < 4; ++ct) {
            const int ctile = cb + (ct << 4);
            const bool tdiag = isdiag && (rtile == ctile);
#pragma unroll
            for (int r = 0; r < 4; ++r) {
                float e = exp2f(acc[rt][ct][r]);
                if (tdiag && ((quad << 2) + r) == l15) e = 0.f; // self-sim
                rs[r] += e;
                cs[ct] += e;
            }
        }
#pragma unroll
        for (int m = 1; m <= 8; m <<= 1)
#pragma unroll
            for (int r = 0; r < 4; ++r) rs[r] += __shfl_xor(rs[r], m, 64);
        if (l15 == 0) {
            int lrow = rb + (rt << 4) + (quad << 2);
#pragma unroll
            for (int r = 0; r < 4; ++r) rsum[wc * 128 + lrow + r] = rs[r];
        }
    }
#pragma unroll
    for (int m = 16; m <= 32; m <<= 1)
#pragma unroll
        for (int ct = 0; ct < 4; ++ct) cs[ct] += __shfl_xor(cs[ct], m, 64);
    if (quad == 0) {
#pragma unroll
        for (int ct = 0; ct < 4; ++ct) csum[wr * 128 + cb + (ct << 4) + l15] = cs[ct];
    }
    __syncthreads();
    if (tid < 128) {
        float rv = rsum[tid] + rsum[128 + tid];
        part[(size_t)bcol * NTOT + brow * 128 + tid] = rv;
        if (!isdiag) {
            float cv = csum[tid] + csum[128 + tid];
            part[(size_t)brow * NTOT + bcol * 128 + tid] = cv;
        }
    }
}

// ---------------- kernel 3: reduce partials per row, take log ----------------
__global__ __launch_bounds__(64) void rowlog(const float* __restrict__ part,
                                             float* __restrict__ logpart) {
    const int row = blockIdx.x * 64 + threadIdx.x;
    float s = 0.f;
#pragma unroll 8
    for (int c = 0; c < 128; ++c) s += part[(size_t)c * NTOT + row];
    float lg = logf(s + 1e-12f);
#pragma unroll
    for (int m = 32; m >= 1; m >>= 1) lg += __shfl_xor(lg, m, 64);
    if (threadIdx.x == 0) logpart[blockIdx.x] = lg;
}

// ---------------- kernel 4: finalize ----------------
__global__ __launch_bounds__(256) void finalk(const float* __restrict__ pospart,
                                              const float* __restrict__ logpart,
                                              float* __restrict__ out) {
    const int t = threadIdx.x;
    float sp = 0.f;
    for (int k = t; k < 4096; k += 256) sp += pospart[k];
    float sl = logpart[t]; // 256 entries
#pragma unroll
    for (int m = 32; m >= 1; m >>= 1) { sp += __shfl_xor(sp, m, 64); sl += __shfl_xor(sl, m, 64); }
    __shared__ float rp[4], rl[4];
    const int wave = t >> 6, lane = t & 63;
    if (lane == 0) { rp[wave] = sp; rl[wave] = sl; }
    __syncthreads();
    if (t == 0) {
        float P = rp[0] + rp[1] + rp[2] + rp[3];
        float L = rl[0] + rl[1] + rl[2] + rl[3];
        out[0] = (L - P) / 16384.0f;
    }
}

extern "C" void kernel_launch(void* const* d_in, const int* in_sizes, int n_in,
                              void* d_out, int out_size, void* d_ws, size_t ws_size,
                              hipStream_t stream) {
    const float* z1 = (const float*)d_in[0];
    const float* z2 = (const float*)d_in[1];
    const float* z3 = (const float*)d_in[2];
    const float* z4 = (const float*)d_in[3];
    float* out = (float*)d_out;

    char* ws = (char*)d_ws;
    bf16*  zb      = (bf16*)ws;                                  // 8 MB
    float* part    = (float*)(ws + (size_t)(8u << 20));          // 8 MB
    float* pospart = (float*)(ws + (size_t)(16u << 20));         // 16 KB
    float* logpart = (float*)(ws + (size_t)(16u << 20) + 16384); // 1 KB

    norm4k<<<1024, 256, 0, stream>>>(z1, z2, z3, z4, zb, pospart);
    tilek<<<8256, 256, 0, stream>>>(zb, part);
    rowlog<<<256, 64, 0, stream>>>(part, logpart);
    finalk<<<1, 256, 0, stream>>>(pospart, logpart, out);
}

// Round 7
// 195.914 us; speedup vs baseline: 1.3967x; 1.3967x over previous
//
#include <hip/hip_runtime.h>

// NT-Xent loss, B=4096, D=256, N=16384, T=0.5.
// loss = mean_i( -pos_i + log(sum_{j!=i} exp(2*dot(zn_i, zn_j)) + 1e-12) )
//
// R7 = R6 with __launch_bounds__(256,4) restored. R6's (256,5) capped the
// allocator at VGPR=48 < the 64-reg accumulator tile -> scratch spill
// (WRITE_SIZE 463MB, HBM 45%, kernel became spill-bound). (256,4) is the
// R2/R5-verified config: VGPR=64 + AGPR accumulators, zero spill.
// Kept from R6 (both correctness-verified, absmax 0.0):
//  - balanced supertile-sequential triangle decode: grid=8256, consecutive
//    bids fill one 16x16-block supertile at a time -> XCD-balanced + L2-local
//    (fixes R5's 1.87x imbalance, keeps R4-proven ~9MB FETCH locality)
//  - LDS = exactly 32768B, reduction scratch aliased over dead tile LDS
//  - zb prescaled by sqrt(2/ln2): epilogue exp = one v_exp_f32
//
// ws layout:
//   [0, 8MB)            : zb   — l2-normalized z * sqrt(2/ln2), bf16, [16384][256]
//   [8MB, 16MB)         : part — per-colblock row sums, f32, [128][16384]
//   [16MB, 16MB+16KB)   : pospart[4096]
//   [16MB+16KB, +1KB)   : logpart[256]
// Every ws slot is written exactly once per launch -> no memset needed.

typedef __bf16 bf16;
typedef __bf16 bf16x4 __attribute__((ext_vector_type(4)));
typedef __bf16 bf16x8 __attribute__((ext_vector_type(8)));
typedef float  f32x4  __attribute__((ext_vector_type(4)));

#define NTOT 16384
#define DDIM 256
#define PRESCALE 1.69864359f  // sqrt(2/ln2); acc = (2/ln2)*cos_sim, e = exp2(acc)

__device__ __forceinline__ float dot4(float4 a, float4 b) {
    return a.x * b.x + a.y * b.y + a.z * b.z + a.w * b.w;
}

// ---------------- kernel 1: normalize rows -> bf16*sqrt(2/ln2), plus positive pairs ----------------
__global__ __launch_bounds__(256) void norm4k(const float* __restrict__ z1,
                                              const float* __restrict__ z2,
                                              const float* __restrict__ z3,
                                              const float* __restrict__ z4,
                                              bf16* __restrict__ zb,
                                              float* __restrict__ pospart) {
    const int wave = threadIdx.x >> 6;
    const int lane = threadIdx.x & 63;
    const int i    = blockIdx.x * 4 + wave; // 0..4095
    const float4* p1 = (const float4*)(z1 + (size_t)i * DDIM);
    const float4* p2 = (const float4*)(z2 + (size_t)i * DDIM);
    const float4* p3 = (const float4*)(z3 + (size_t)i * DDIM);
    const float4* p4 = (const float4*)(z4 + (size_t)i * DDIM);
    float4 a = p1[lane], b = p2[lane], c = p3[lane], d = p4[lane];
    float s11 = dot4(a, a), s22 = dot4(b, b), s33 = dot4(c, c), s44 = dot4(d, d);
    float s12 = dot4(a, b), s23 = dot4(b, c), s34 = dot4(c, d), s41 = dot4(d, a);
#pragma unroll
    for (int m = 32; m >= 1; m >>= 1) {
        s11 += __shfl_xor(s11, m, 64); s22 += __shfl_xor(s22, m, 64);
        s33 += __shfl_xor(s33, m, 64); s44 += __shfl_xor(s44, m, 64);
        s12 += __shfl_xor(s12, m, 64); s23 += __shfl_xor(s23, m, 64);
        s34 += __shfl_xor(s34, m, 64); s41 += __shfl_xor(s41, m, 64);
    }
    const float m1 = fmaxf(sqrtf(s11), 1e-12f), m2 = fmaxf(sqrtf(s22), 1e-12f);
    const float m3 = fmaxf(sqrtf(s33), 1e-12f), m4 = fmaxf(sqrtf(s44), 1e-12f);
    const float i1 = 1.0f / m1, i2 = 1.0f / m2, i3 = 1.0f / m3, i4 = 1.0f / m4;
    const float a1 = i1 * PRESCALE, a2 = i2 * PRESCALE, a3 = i3 * PRESCALE, a4 = i4 * PRESCALE;
    bf16x4 o;
    o.x = (bf16)(a.x * a1); o.y = (bf16)(a.y * a1); o.z = (bf16)(a.z * a1); o.w = (bf16)(a.w * a1);
    *(bf16x4*)(zb + (size_t)i * DDIM + lane * 4) = o;
    o.x = (bf16)(b.x * a2); o.y = (bf16)(b.y * a2); o.z = (bf16)(b.z * a2); o.w = (bf16)(b.w * a2);
    *(bf16x4*)(zb + (size_t)(i + 4096) * DDIM + lane * 4) = o;
    o.x = (bf16)(c.x * a3); o.y = (bf16)(c.y * a3); o.z = (bf16)(c.z * a3); o.w = (bf16)(c.w * a3);
    *(bf16x4*)(zb + (size_t)(i + 8192) * DDIM + lane * 4) = o;
    o.x = (bf16)(d.x * a4); o.y = (bf16)(d.y * a4); o.z = (bf16)(d.z * a4); o.w = (bf16)(d.w * a4);
    *(bf16x4*)(zb + (size_t)(i + 12288) * DDIM + lane * 4) = o;
    if (lane == 0)
        pospart[i] = 2.0f * (s12 * i1 * i2 + s23 * i2 * i3 + s34 * i3 * i4 + s41 * i4 * i1);
}

// ---------------- kernel 2: fused Gram exp-rowsum, balanced supertile triangle ----------------
// 128x128 tile per block; 4 waves in 2x2 of 64x64; mfma_f32_16x16x32_bf16.
// LDS granule-xor swizzle: granule g of row r stored at slot (g ^ (r&7)).
__global__ __launch_bounds__(256, 4) void tilek(const bf16* __restrict__ zb,
                                                float* __restrict__ part) {
    __shared__ __attribute__((aligned(16))) char lds[32768]; // A:[0,16K) B:[16K,32K)
    // reduction scratch aliased over dead tile LDS after the final K-barrier:
    float* rsum = (float*)lds;            // [2][128] (indexed by wc)
    float* csum = (float*)(lds + 1024);   // [2][128] (indexed by wr)

    const int tid  = threadIdx.x;
    const int wave = tid >> 6;
    const int lane = tid & 63;

    // Balanced supertile-sequential triangle decode (8x8 supertiles of 16x16
    // blocks). Supertile row r: diag supertile (136 triangle blocks) then
    // (7-r) full off-diag supertiles (256 each). Consecutive bids share a
    // supertile -> all XCDs work the same ~2MB set; zero early exits.
    int rem = blockIdx.x;
    int sr = 0;
#pragma unroll
    for (int r = 0; r < 7; ++r) {
        int rowblocks = 136 + (7 - sr) * 256;
        if (rem >= rowblocks) { rem -= rowblocks; ++sr; }
    }
    int brow, bcol;
    if (rem < 136) {  // diagonal supertile (sr,sr): 16-row triangle
        int i = 0;
#pragma unroll
        for (int r = 0; r < 15; ++r) {
            if (rem >= 16 - i) { rem -= 16 - i; ++i; }
        }
        brow = sr * 16 + i;
        bcol = sr * 16 + i + rem;
    } else {
        int e  = rem - 136;
        int sc = sr + 1 + (e >> 8);
        int w  = e & 255;
        brow = sr * 16 + (w >> 4);
        bcol = sc * 16 + (w & 15);
    }
    const bool isdiag = (brow == bcol);

    const char* gA = (const char*)zb + (size_t)brow * 128 * 512; // row stride 512B
    const char* gB = (const char*)zb + (size_t)bcol * 128 * 512;

    const int quad = lane >> 4;
    const int l15  = lane & 15;
    const int wr   = wave >> 1, wc = wave & 1;

    f32x4 zero = {0.f, 0.f, 0.f, 0.f};
    f32x4 acc[4][4];
#pragma unroll
    for (int a = 0; a < 4; ++a)
#pragma unroll
        for (int b = 0; b < 4; ++b) acc[a][b] = zero;

    const int strow = lane >> 3;  // row within 8-row chunk
    const int sslot = lane & 7;   // swizzled granule slot this lane fills

    for (int ko = 0; ko < 4; ++ko) {
        // stage A and B 128x64 slices (16KB each); 4+4 1KB wave-loads per wave
#pragma unroll
        for (int s4 = 0; s4 < 4; ++s4) {
            int t   = (wave << 2) + s4;        // 0..15
            int row = (t << 3) + strow;        // 0..127
            int g   = sslot ^ (row & 7);       // global granule to fetch
            size_t goff = (size_t)row * 512 + ko * 128 + g * 16;
            __builtin_amdgcn_global_load_lds(
                (const __attribute__((address_space(1))) unsigned int*)(gA + goff),
                (__attribute__((address_space(3))) unsigned int*)(lds + t * 1024),
                16, 0, 0);
            __builtin_amdgcn_global_load_lds(
                (const __attribute__((address_space(1))) unsigned int*)(gB + goff),
                (__attribute__((address_space(3))) unsigned int*)(lds + 16384 + t * 1024),
                16, 0, 0);
        }
        __syncthreads();
#pragma unroll
        for (int ks = 0; ks < 2; ++ks) {
            bf16x8 af[4], bfr[4];
            const int gg = (ks << 2) + quad;   // granule within 64-col slice
#pragma unroll
            for (int rt = 0; rt < 4; ++rt) {
                int arow = (wr << 6) + (rt << 4) + l15;
                int addr = arow * 128 + ((gg ^ (arow & 7)) << 4);
                af[rt] = *(const bf16x8*)(lds + addr);
            }
#pragma unroll
            for (int ct = 0; ct < 4; ++ct) {
                int brw  = (wc << 6) + (ct << 4) + l15;
                int addr = 16384 + brw * 128 + ((gg ^ (brw & 7)) << 4);
                bfr[ct] = *(const bf16x8*)(lds + addr);
            }
#pragma unroll
            for (int rt = 0; rt < 4; ++rt)
#pragma unroll
                for (int ct = 0; ct < 4; ++ct)
                    acc[rt][ct] = __builtin_amdgcn_mfma_f32_16x16x32_bf16(
                        af[rt], bfr[ct], acc[rt][ct], 0, 0, 0);
        }
        __syncthreads();   // final iter: all tile reads done -> scratch aliasing safe
    }

    // epilogue: e = exp2(acc) (inputs pre-scaled by sqrt(2/ln2)); mask diagonal;
    // row-sums over lane&15, col-sums over quad.
    const int rb = wr << 6;
    const int cb = wc << 6;
    float cs[4] = {0.f, 0.f, 0.f, 0.f};
#pragma unroll
    for (int rt = 0; rt < 4; ++rt) {
        float rs[4] = {0.f, 0.f, 0.f, 0.f};
        const int rtile = rb + (rt << 4);
#pragma unroll
        for (int ct = 0; ct < 4; ++ct) {
            const int ctile = cb + (ct << 4);
            const bool tdiag = isdiag && (rtile == ctile);
#pragma unroll
            for (int r = 0; r < 4; ++r) {
                float e = exp2f(acc[rt][ct][r]);
                if (tdiag && ((quad << 2) + r) == l15) e = 0.f; // self-sim
                rs[r] += e;
                cs[ct] += e;
            }
        }
#pragma unroll
        for (int m = 1; m <= 8; m <<= 1)
#pragma unroll
            for (int r = 0; r < 4; ++r) rs[r] += __shfl_xor(rs[r], m, 64);
        if (l15 == 0) {
            int lrow = rb + (rt << 4) + (quad << 2);
#pragma unroll
            for (int r = 0; r < 4; ++r) rsum[wc * 128 + lrow + r] = rs[r];
        }
    }
#pragma unroll
    for (int m = 16; m <= 32; m <<= 1)
#pragma unroll
        for (int ct = 0; ct < 4; ++ct) cs[ct] += __shfl_xor(cs[ct], m, 64);
    if (quad == 0) {
#pragma unroll
        for (int ct = 0; ct < 4; ++ct) csum[wr * 128 + cb + (ct << 4) + l15] = cs[ct];
    }
    __syncthreads();
    if (tid < 128) {
        float rv = rsum[tid] + rsum[128 + tid];
        part[(size_t)bcol * NTOT + brow * 128 + tid] = rv;
        if (!isdiag) {
            float cv = csum[tid] + csum[128 + tid];
            part[(size_t)brow * NTOT + bcol * 128 + tid] = cv;
        }
    }
}

// ---------------- kernel 3: reduce partials per row, take log ----------------
__global__ __launch_bounds__(64) void rowlog(const float* __restrict__ part,
                                             float* __restrict__ logpart) {
    const int row = blockIdx.x * 64 + threadIdx.x;
    float s = 0.f;
#pragma unroll 8
    for (int c = 0; c < 128; ++c) s += part[(size_t)c * NTOT + row];
    float lg = logf(s + 1e-12f);
#pragma unroll
    for (int m = 32; m >= 1; m >>= 1) lg += __shfl_xor(lg, m, 64);
    if (threadIdx.x == 0) logpart[blockIdx.x] = lg;
}

// ---------------- kernel 4: finalize ----------------
__global__ __launch_bounds__(256) void finalk(const float* __restrict__ pospart,
                                              const float* __restrict__ logpart,
                                              float* __restrict__ out) {
    const int t = threadIdx.x;
    float sp = 0.f;
    for (int k = t; k < 4096; k += 256) sp += pospart[k];
    float sl = logpart[t]; // 256 entries
#pragma unroll
    for (int m = 32; m >= 1; m >>= 1) { sp += __shfl_xor(sp, m, 64); sl += __shfl_xor(sl, m, 64); }
    __shared__ float rp[4], rl[4];
    const int wave = t >> 6, lane = t & 63;
    if (lane == 0) { rp[wave] = sp; rl[wave] = sl; }
    __syncthreads();
    if (t == 0) {
        float P = rp[0] + rp[1] + rp[2] + rp[3];
        float L = rl[0] + rl[1] + rl[2] + rl[3];
        out[0] = (L - P) / 16384.0f;
    }
}

extern "C" void kernel_launch(void* const* d_in, const int* in_sizes, int n_in,
                              void* d_out, int out_size, void* d_ws, size_t ws_size,
                              hipStream_t stream) {
    const float* z1 = (const float*)d_in[0];
    const float* z2 = (const float*)d_in[1];
    const float* z3 = (const float*)d_in[2];
    const float* z4 = (const float*)d_in[3];
    float* out = (float*)d_out;

    char* ws = (char*)d_ws;
    bf16*  zb      = (bf16*)ws;                                  // 8 MB
    float* part    = (float*)(ws + (size_t)(8u << 20));          // 8 MB
    float* pospart = (float*)(ws + (size_t)(16u << 20));         // 16 KB
    float* logpart = (float*)(ws + (size_t)(16u << 20) + 16384); // 1 KB

    norm4k<<<1024, 256, 0, stream>>>(z1, z2, z3, z4, zb, pospart);
    tilek<<<8256, 256, 0, stream>>>(zb, part);
    rowlog<<<256, 64, 0, stream>>>(part, logpart);
    finalk<<<1, 256, 0, stream>>>(pospart, logpart, out);
}